// Round 1
// baseline (333.562 us; speedup 1.0000x reference)
//
#include <hip/hip_runtime.h>
#include <hip/hip_bf16.h>

// B=16, N=2048, DIM=256. out[b,i,j] = <pn_i, pn_j>, pn = normalize(x@W^T + b).
// Strategy: bf16 MFMA for both matmuls (fp32 accumulate); threshold 2e-2 >> bf16 err ~1e-2.

typedef __bf16 bf16x8 __attribute__((ext_vector_type(8)));
typedef float  f32x4  __attribute__((ext_vector_type(4)));

__device__ __forceinline__ void gl_lds16(const void* g, void* l) {
  __builtin_amdgcn_global_load_lds((const __attribute__((address_space(1))) void*)g,
                                   (__attribute__((address_space(3))) void*)l, 16, 0, 0);
}

__device__ __forceinline__ bf16x8 pack8(f32x4 a, f32x4 b) {
  bf16x8 r;
  r[0] = (__bf16)a[0]; r[1] = (__bf16)a[1]; r[2] = (__bf16)a[2]; r[3] = (__bf16)a[3];
  r[4] = (__bf16)b[0]; r[5] = (__bf16)b[1]; r[6] = (__bf16)b[2]; r[7] = (__bf16)b[3];
  return r;
}

// ---------------- Kernel 1: p = x@W^T + b ; pn = p/||p|| -> bf16 ----------------
// 512 threads = 8 waves; 128 x-rows per block; grid = 32768/128 = 256.
// W staged to LDS as bf16, rows (=output col e) 512B apart, XOR-swizzled (G4).
__global__ __launch_bounds__(512, 1) void proj_kernel(
    const float* __restrict__ x, const float* __restrict__ W,
    const float* __restrict__ bq, __bf16* __restrict__ pn) {
  __shared__ __attribute__((aligned(16))) char ldsW[131072];  // 256x256 bf16 swizzled
  const int t = threadIdx.x;
  const int lane = t & 63;
  const int w = t >> 6;

  // ---- stage W (fp32 -> bf16) into LDS, swizzled: byte ^= (row&7)<<4 ----
  #pragma unroll
  for (int it = 0; it < 16; ++it) {
    int base = (it * 512 + t) * 8;          // element index, 8 contiguous per thread
    int row  = base >> 8;                   // e index
    int colb = (base & 255) * 2;            // byte offset in row (16B aligned)
    f32x4 v0 = *(const f32x4*)(W + base);
    f32x4 v1 = *(const f32x4*)(W + base + 4);
    *(bf16x8*)(ldsW + row * 512 + (colb ^ ((row & 7) << 4))) = pack8(v0, v1);
  }
  __syncthreads();

  // ---- A fragments: 16 x-rows per wave, K=256 (8 steps of 32) ----
  const int r0 = blockIdx.x * 128 + w * 16;
  const int arow = r0 + (lane & 15);
  const float* xrow = x + (size_t)arow * 256 + (lane >> 4) * 8;
  bf16x8 afr[8];
  #pragma unroll
  for (int kk = 0; kk < 8; ++kk) {
    f32x4 v0 = *(const f32x4*)(xrow + kk * 32);
    f32x4 v1 = *(const f32x4*)(xrow + kk * 32 + 4);
    afr[kk] = pack8(v0, v1);
  }

  // ---- 16 col-tiles of 16 output features each ----
  f32x4 acc[16];
  #pragma unroll
  for (int ct = 0; ct < 16; ++ct) acc[ct] = (f32x4){0.f, 0.f, 0.f, 0.f};
  const int kb0 = (lane >> 4) * 16;
  #pragma unroll
  for (int ct = 0; ct < 16; ++ct) {
    int brow = ct * 16 + (lane & 15);
    const char* wb = ldsW + brow * 512;
    int sw = (brow & 7) << 4;
    #pragma unroll
    for (int kk = 0; kk < 8; ++kk) {
      bf16x8 bf = *(const bf16x8*)(wb + ((kk * 64 + kb0) ^ sw));
      acc[ct] = __builtin_amdgcn_mfma_f32_16x16x32_bf16(afr[kk], bf, acc[ct], 0, 0, 0);
    }
  }

  // ---- bias, row-norm (16-lane group reduce), normalize, store bf16 ----
  float bc[16];
  #pragma unroll
  for (int ct = 0; ct < 16; ++ct) bc[ct] = bq[ct * 16 + (lane & 15)];
  #pragma unroll
  for (int ct = 0; ct < 16; ++ct) {
    #pragma unroll
    for (int r = 0; r < 4; ++r) acc[ct][r] += bc[ct];
  }
  #pragma unroll
  for (int r = 0; r < 4; ++r) {
    float s = 0.f;
    #pragma unroll
    for (int ct = 0; ct < 16; ++ct) s += acc[ct][r] * acc[ct][r];
    s += __shfl_xor(s, 1); s += __shfl_xor(s, 2);
    s += __shfl_xor(s, 4); s += __shfl_xor(s, 8);
    float rn = rsqrtf(s);
    int rowg = r0 + (lane >> 4) * 4 + r;
    __bf16* dst = pn + (size_t)rowg * 256 + (lane & 15);
    #pragma unroll
    for (int ct = 0; ct < 16; ++ct) dst[ct * 16] = (__bf16)(acc[ct][r] * rn);
  }
}

// ---------------- Kernel 2: attn[b] = pn[b] @ pn[b]^T ----------------
// 128x128 tile per block, K=256 fully LDS-resident. 8 waves, each 64x32.
// Staging: global_load_lds w=16, linear LDS dest + pre-swizzled global source (rule #21).
__global__ __launch_bounds__(512, 1) void gram_kernel(
    const __bf16* __restrict__ pn, float* __restrict__ out) {
  __shared__ __attribute__((aligned(16))) char lds[131072];  // [0,64K)=A, [64K,128K)=B
  const int t = threadIdx.x;
  const int lane = t & 63;
  const int w = t >> 6;
  const int bid = blockIdx.x;
  const int batch = bid >> 8;
  const int ti = (bid >> 4) & 15;
  const int tj = bid & 15;
  const char* pb = (const char*)(pn + (size_t)batch * 2048 * 256);

  // ---- stage A tile (rows ti*128..+128) and B tile (rows tj*128..+128) ----
  #pragma unroll
  for (int i = 0; i < 8; ++i) {
    int off = ((w * 8 + i) * 64 + lane) * 16;  // byte offset within 64KB region
    int row = off >> 9;                        // tile-local row (512B rows)
    int kb  = off & 511;
    gl_lds16(pb + (size_t)(ti * 128 + row) * 512 + (kb ^ ((row & 7) << 4)),
             lds + (w * 8 + i) * 1024);
  }
  #pragma unroll
  for (int i = 0; i < 8; ++i) {
    int off = ((w * 8 + i) * 64 + lane) * 16;
    int row = off >> 9;
    int kb  = off & 511;
    gl_lds16(pb + (size_t)(tj * 128 + row) * 512 + (kb ^ ((row & 7) << 4)),
             lds + 65536 + (w * 8 + i) * 1024);
  }
  asm volatile("s_waitcnt vmcnt(0)" ::: "memory");
  __syncthreads();

  // ---- compute: wave (wr,wc) owns 64x32 of the 128x128 tile ----
  const int wr = w >> 2;   // 0..1
  const int wc = w & 3;    // 0..3
  f32x4 acc[4][2];
  #pragma unroll
  for (int m = 0; m < 4; ++m)
    #pragma unroll
    for (int n = 0; n < 2; ++n) acc[m][n] = (f32x4){0.f, 0.f, 0.f, 0.f};

  const int la0 = wr * 64 + (lane & 15);
  const int lb0 = wc * 32 + (lane & 15);
  const int kb0 = (lane >> 4) * 16;
  const char* ldsA = lds;
  const char* ldsB = lds + 65536;
  #pragma unroll
  for (int kk = 0; kk < 8; ++kk) {
    int kb = kk * 64 + kb0;
    bf16x8 a[4], bfr[2];
    #pragma unroll
    for (int m = 0; m < 4; ++m) {
      int row = la0 + m * 16;
      a[m] = *(const bf16x8*)(ldsA + row * 512 + (kb ^ ((row & 7) << 4)));
    }
    #pragma unroll
    for (int n = 0; n < 2; ++n) {
      int row = lb0 + n * 16;
      bfr[n] = *(const bf16x8*)(ldsB + row * 512 + (kb ^ ((row & 7) << 4)));
    }
    #pragma unroll
    for (int m = 0; m < 4; ++m)
      #pragma unroll
      for (int n = 0; n < 2; ++n)
        acc[m][n] = __builtin_amdgcn_mfma_f32_16x16x32_bf16(a[m], bfr[n], acc[m][n], 0, 0, 0);
  }

  // ---- store fp32: C/D layout col=lane&15, row=(lane>>4)*4+r (m89) ----
  float* ob = out + (size_t)batch * 2048 * 2048;
  const int ro0 = ti * 128 + wr * 64 + (lane >> 4) * 4;
  const int co0 = tj * 128 + wc * 32 + (lane & 15);
  #pragma unroll
  for (int m = 0; m < 4; ++m)
    #pragma unroll
    for (int n = 0; n < 2; ++n)
      #pragma unroll
      for (int r = 0; r < 4; ++r)
        ob[(size_t)(ro0 + m * 16 + r) * 2048 + (co0 + n * 16)] = acc[m][n][r];
}

extern "C" void kernel_launch(void* const* d_in, const int* in_sizes, int n_in,
                              void* d_out, int out_size, void* d_ws, size_t ws_size,
                              hipStream_t stream) {
  const float* x  = (const float*)d_in[0];   // [16,2048,256]
  const float* Wq = (const float*)d_in[1];   // [256,256]
  const float* bq = (const float*)d_in[2];   // [256]
  float* out = (float*)d_out;                // [16,2048,2048]
  __bf16* pn = (__bf16*)d_ws;                // 32768*256 bf16 = 16 MB scratch

  proj_kernel<<<dim3(256), dim3(512), 0, stream>>>(x, Wq, bq, pn);
  gram_kernel<<<dim3(4096), dim3(512), 0, stream>>>(pn, out);
}